// Round 1
// baseline (1140.693 us; speedup 1.0000x reference)
//
#include <hip/hip_runtime.h>
#include <math.h>

// ---------------- workspace layout (float offsets) ----------------
#define WS_POOLED 0        // 32*64   = 2048
#define WS_CIN    2048     // 32*64     (w1 * ch_att)
#define WS_COUT   4096     // 32*64     (w2 * f_att)
#define WS_SP9    6144     // 32*9
#define WS_K4     6432     // 32*4
#define WS_WF     8192     // 32*64*64*9 = 1179648  (fused per-sample conv weight)
// total ~1.19M floats = 4.75 MB

// ---------------- 1) global average pool: pooled[b,c] ----------------
__global__ __launch_bounds__(256) void pool_kernel(const float* __restrict__ x,
                                                   float* __restrict__ pooled) {
  const int bc = blockIdx.x;              // b*64 + c  (2048 blocks)
  const int tid = threadIdx.x;
  const float4* p = (const float4*)(x + (size_t)bc * 16384);
  float s = 0.f;
  for (int j = tid; j < 4096; j += 256) {
    float4 v = p[j];
    s += (v.x + v.y) + (v.z + v.w);
  }
#pragma unroll
  for (int off = 32; off > 0; off >>= 1) s += __shfl_down(s, off, 64);
  __shared__ float red[4];
  if ((tid & 63) == 0) red[tid >> 6] = s;
  __syncthreads();
  if (tid == 0) pooled[bc] = (red[0] + red[1] + red[2] + red[3]) * (1.f / 16384.f);
}

// ---------------- 2) attention chain, one block per batch ----------------
__global__ __launch_bounds__(128) void att_kernel(
    const float* __restrict__ fc_w, const float* __restrict__ ch_w, const float* __restrict__ ch_b,
    const float* __restrict__ f_w,  const float* __restrict__ f_b,
    const float* __restrict__ sp_w, const float* __restrict__ sp_b,
    const float* __restrict__ k_w,  const float* __restrict__ k_b,
    const float* __restrict__ fus_w1, const float* __restrict__ fus_b1,
    const float* __restrict__ fus_w2, const float* __restrict__ fus_b2,
    float* __restrict__ ws) {
  const int b = blockIdx.x;
  const int t = threadIdx.x;
  __shared__ float s_pool[64], s_a[16], s_att[128], s_sp[9], s_k[4], s_h[8],
      s_att2[128], s_red[2], s_w12[2];

  if (t < 64) s_pool[t] = ws[WS_POOLED + b * 64 + t];
  __syncthreads();

  if (t < 16) {   // a = relu(pooled @ fc_w.T)
    float s = 0.f;
    for (int c = 0; c < 64; ++c) s += s_pool[c] * fc_w[t * 64 + c];
    s_a[t] = fmaxf(s, 0.f);
  }
  __syncthreads();

  if (t < 64) {   // ch_att
    float s = ch_b[t];
    for (int j = 0; j < 16; ++j) s += s_a[j] * ch_w[t * 16 + j];
    s_att[t] = 1.f / (1.f + expf(-s));
  } else {        // f_att
    const int o = t - 64;
    float s = f_b[o];
    for (int j = 0; j < 16; ++j) s += s_a[j] * f_w[o * 16 + j];
    s_att[t] = 1.f / (1.f + expf(-s));
  }
  if (t < 9) {    // sp_att
    float s = sp_b[t];
    for (int j = 0; j < 16; ++j) s += s_a[j] * sp_w[t * 16 + j];
    s_sp[t] = 1.f / (1.f + expf(-s));
  }
  if (t < 4) {    // k logits
    float s = k_b[t];
    for (int j = 0; j < 16; ++j) s += s_a[j] * k_w[t * 16 + j];
    s_k[t] = s;
  }
  __syncthreads();

  if (t < 8) {    // h = relu(att @ fus_w1.T + b1)
    float s = fus_b1[t];
    for (int c = 0; c < 128; ++c) s += s_att[c] * fus_w1[t * 128 + c];
    s_h[t] = fmaxf(s, 0.f);
  }
  if (t == 127) { // softmax over 4 kernel logits
    float m = fmaxf(fmaxf(s_k[0], s_k[1]), fmaxf(s_k[2], s_k[3]));
    float e0 = expf(s_k[0] - m), e1 = expf(s_k[1] - m);
    float e2 = expf(s_k[2] - m), e3 = expf(s_k[3] - m);
    float inv = 1.f / (e0 + e1 + e2 + e3);
    s_k[0] = e0 * inv; s_k[1] = e1 * inv; s_k[2] = e2 * inv; s_k[3] = e3 * inv;
  }
  __syncthreads();

  { // att2 = sigmoid(h @ fus_w2.T + b2), 128 wide
    float s = fus_b2[t];
    for (int j = 0; j < 8; ++j) s += s_h[j] * fus_w2[t * 8 + j];
    s_att2[t] = 1.f / (1.f + expf(-s));
  }
  __syncthreads();

  if (t < 2) {
    float s = 0.f;
    for (int c = 0; c < 64; ++c) s += s_att2[t * 64 + c];
    s_red[t] = s;
  }
  __syncthreads();
  if (t == 0) {
    float m = fmaxf(s_red[0], s_red[1]);
    float e1 = expf(s_red[0] - m), e2 = expf(s_red[1] - m);
    float inv = 1.f / (e1 + e2);
    s_w12[0] = e1 * inv;  // score for x branch (w1)
    s_w12[1] = e2 * inv;  // score for out branch (w2)
  }
  __syncthreads();

  if (t < 64) {
    ws[WS_CIN  + b * 64 + t] = s_w12[0] * s_att[t];        // w1 * ch_att
    ws[WS_COUT + b * 64 + t] = s_w12[1] * s_att[64 + t];   // w2 * f_att
  }
  if (t < 9) ws[WS_SP9 + b * 9 + t] = s_sp[t];
  if (t < 4) ws[WS_K4 + b * 4 + t] = s_k[t];
}

// ---------------- 3) fuse everything into per-sample weight ----------------
// Wf[b,o,i,p,q] = (w2*f_att[o]) * sp[p,q] * (sum_k k_att[k]*weight[k,o,i,p,q]) * (w1*ch_att[i])
__global__ __launch_bounds__(256) void wf_kernel(const float* __restrict__ weight,
                                                 const float* __restrict__ ws,
                                                 float* __restrict__ wf) {
  const int bo = blockIdx.x;              // b*64 + o  (2048 blocks)
  const int b = bo >> 6, o = bo & 63;
  const float co = ws[WS_COUT + b * 64 + o];
  const float k0 = ws[WS_K4 + b * 4 + 0], k1 = ws[WS_K4 + b * 4 + 1];
  const float k2 = ws[WS_K4 + b * 4 + 2], k3 = ws[WS_K4 + b * 4 + 3];
  for (int idx = threadIdx.x; idx < 576; idx += 256) {
    const int i = idx / 9, pq = idx - i * 9;
    const size_t wi = ((size_t)o * 64 + i) * 9 + pq;
    float s = k0 * weight[wi] + k1 * weight[36864 + wi] +
              k2 * weight[73728 + wi] + k3 * weight[110592 + wi];
    wf[(size_t)bo * 576 + idx] = co * ws[WS_SP9 + b * 9 + pq] * ws[WS_CIN + b * 64 + i] * s;
  }
}

// ---------------- 4) per-sample 3x3 conv (pad 1), fp32 tiled ----------------
// block: batch b, 8 out channels, 32x64 spatial tile. thread: 2x4 pixels x 8 oc.
__global__ __launch_bounds__(256, 2) void conv_kernel(const float* __restrict__ x,
                                                      const float* __restrict__ wf,
                                                      float* __restrict__ out) {
  const int bx = blockIdx.x;
  const int tw = bx & 1;            // 2 tiles of 64 cols
  const int th = (bx >> 1) & 3;     // 4 tiles of 32 rows
  const int og = (bx >> 3) & 7;     // 8 groups of 8 out channels
  const int b  = bx >> 6;           // 32 batches
  const int tid = threadIdx.x;
  const int tx = tid & 15;
  const int ty = tid >> 4;
  const int h0 = th * 32, w0 = tw * 64;
  const int pr = 2 * ty, pc = 4 * tx;   // this thread's pixel block in tile

  __shared__ __align__(16) float sx[2][34][68];   // 2 in-ch, 34x66 halo tile (row pad->68)
  __shared__ __align__(16) float sw[8][2][12];    // 8 oc x 2 ic x 3x3 (row pad->4)

  float acc[8][8];
#pragma unroll
  for (int o = 0; o < 8; ++o)
#pragma unroll
    for (int p = 0; p < 8; ++p) acc[o][p] = 0.f;

  for (int ci = 0; ci < 64; ci += 2) {
    // stage x: 2 channels, rows h0-1..h0+32, cols w0-1..w0+64 (zero pad OOB)
    for (int idx = tid; idx < 2 * 34 * 66; idx += 256) {
      const int i = idx / (34 * 66);
      const int rem = idx - i * (34 * 66);
      const int r = rem / 66;
      const int c = rem - r * 66;
      const int gh = h0 + r - 1, gw = w0 + c - 1;
      float v = 0.f;
      if ((unsigned)gh < 128u && (unsigned)gw < 128u)
        v = x[((size_t)(b * 64 + ci + i) * 128 + gh) * 128 + gw];
      sx[i][r][c] = v;
    }
    // stage weights: 8 oc x 2 ic x 9
    if (tid < 144) {
      const int o = tid / 18;
      const int rem = tid - o * 18;
      const int i = rem / 9;
      const int pq = rem - i * 9;
      const int p = pq / 3, q = pq - p * 3;
      sw[o][i][p * 4 + q] = wf[((size_t)(b * 64 + og * 8 + o) * 64 + (ci + i)) * 9 + pq];
    }
    __syncthreads();

#pragma unroll
    for (int i = 0; i < 2; ++i) {
      float xv[4][6];
#pragma unroll
      for (int r = 0; r < 4; ++r) {
        float4 t0 = *(const float4*)&sx[i][pr + r][pc];
        float2 t1 = *(const float2*)&sx[i][pr + r][pc + 4];
        xv[r][0] = t0.x; xv[r][1] = t0.y; xv[r][2] = t0.z; xv[r][3] = t0.w;
        xv[r][4] = t1.x; xv[r][5] = t1.y;
      }
#pragma unroll
      for (int o = 0; o < 8; ++o) {
        const float w00 = sw[o][i][0], w01 = sw[o][i][1], w02 = sw[o][i][2];
        const float w10 = sw[o][i][4], w11 = sw[o][i][5], w12 = sw[o][i][6];
        const float w20 = sw[o][i][8], w21 = sw[o][i][9], w22 = sw[o][i][10];
#pragma unroll
        for (int dr = 0; dr < 2; ++dr) {
#pragma unroll
          for (int dc = 0; dc < 4; ++dc) {
            float s = acc[o][dr * 4 + dc];
            s = fmaf(w00, xv[dr][dc],     s);
            s = fmaf(w01, xv[dr][dc + 1], s);
            s = fmaf(w02, xv[dr][dc + 2], s);
            s = fmaf(w10, xv[dr + 1][dc],     s);
            s = fmaf(w11, xv[dr + 1][dc + 1], s);
            s = fmaf(w12, xv[dr + 1][dc + 2], s);
            s = fmaf(w20, xv[dr + 2][dc],     s);
            s = fmaf(w21, xv[dr + 2][dc + 1], s);
            s = fmaf(w22, xv[dr + 2][dc + 2], s);
            acc[o][dr * 4 + dc] = s;
          }
        }
      }
    }
    __syncthreads();
  }

#pragma unroll
  for (int o = 0; o < 8; ++o) {
#pragma unroll
    for (int dr = 0; dr < 2; ++dr) {
      float4 v = make_float4(acc[o][dr * 4 + 0], acc[o][dr * 4 + 1],
                             acc[o][dr * 4 + 2], acc[o][dr * 4 + 3]);
      *(float4*)&out[((size_t)(b * 64 + og * 8 + o) * 128 + (h0 + pr + dr)) * 128 +
                     (w0 + pc)] = v;
    }
  }
}

extern "C" void kernel_launch(void* const* d_in, const int* in_sizes, int n_in,
                              void* d_out, int out_size, void* d_ws, size_t ws_size,
                              hipStream_t stream) {
  const float* x      = (const float*)d_in[0];
  const float* fc_w   = (const float*)d_in[1];
  const float* ch_w   = (const float*)d_in[2];
  const float* ch_b   = (const float*)d_in[3];
  const float* f_w    = (const float*)d_in[4];
  const float* f_b    = (const float*)d_in[5];
  const float* sp_w   = (const float*)d_in[6];
  const float* sp_b   = (const float*)d_in[7];
  const float* k_w    = (const float*)d_in[8];
  const float* k_b    = (const float*)d_in[9];
  const float* fus_w1 = (const float*)d_in[10];
  const float* fus_b1 = (const float*)d_in[11];
  const float* fus_w2 = (const float*)d_in[12];
  const float* fus_b2 = (const float*)d_in[13];
  const float* weight = (const float*)d_in[14];
  float* ws  = (float*)d_ws;
  float* out = (float*)d_out;

  pool_kernel<<<2048, 256, 0, stream>>>(x, ws + WS_POOLED);
  att_kernel<<<32, 128, 0, stream>>>(fc_w, ch_w, ch_b, f_w, f_b, sp_w, sp_b,
                                     k_w, k_b, fus_w1, fus_b1, fus_w2, fus_b2, ws);
  wf_kernel<<<2048, 256, 0, stream>>>(weight, ws, ws + WS_WF);
  conv_kernel<<<2048, 256, 0, stream>>>(x, ws + WS_WF, out);
}

// Round 2
// 137.310 us; speedup vs baseline: 8.3074x; 8.3074x over previous
//
#include <hip/hip_runtime.h>
#include <math.h>
#include <stdint.h>

typedef short bf16x8 __attribute__((ext_vector_type(8)));
typedef float f32x16 __attribute__((ext_vector_type(16)));

// ---------------- workspace layout (float offsets) ----------------
#define WS_POOLED 0        // 32*64
#define WS_CIN    2048     // 32*64   (w1 * ch_att)
#define WS_COUT   4096     // 32*64   (w2 * f_att)
#define WS_SP9    6144     // 32*9
#define WS_K4     6432     // 32*4
#define WS_WF     8192     // bf16 region: 32*9*64*64 ushort = 2.36 MB

static __device__ __forceinline__ unsigned f2bf(float f) {
  unsigned u = __builtin_bit_cast(unsigned, f);
  return (u + 0x7FFFu + ((u >> 16) & 1u)) >> 16;   // RNE
}

// ---------------- 1) global average pool ----------------
__global__ __launch_bounds__(256) void pool_kernel(const float* __restrict__ x,
                                                   float* __restrict__ pooled) {
  const int bc = blockIdx.x;
  const int tid = threadIdx.x;
  const float4* p = (const float4*)(x + (size_t)bc * 16384);
  float s = 0.f;
  for (int j = tid; j < 4096; j += 256) {
    float4 v = p[j];
    s += (v.x + v.y) + (v.z + v.w);
  }
#pragma unroll
  for (int off = 32; off > 0; off >>= 1) s += __shfl_down(s, off, 64);
  __shared__ float red[4];
  if ((tid & 63) == 0) red[tid >> 6] = s;
  __syncthreads();
  if (tid == 0) pooled[bc] = (red[0] + red[1] + red[2] + red[3]) * (1.f / 16384.f);
}

// ---------------- 2) attention chain, one block per batch ----------------
__global__ __launch_bounds__(128) void att_kernel(
    const float* __restrict__ fc_w, const float* __restrict__ ch_w, const float* __restrict__ ch_b,
    const float* __restrict__ f_w,  const float* __restrict__ f_b,
    const float* __restrict__ sp_w, const float* __restrict__ sp_b,
    const float* __restrict__ k_w,  const float* __restrict__ k_b,
    const float* __restrict__ fus_w1, const float* __restrict__ fus_b1,
    const float* __restrict__ fus_w2, const float* __restrict__ fus_b2,
    float* __restrict__ ws) {
  const int b = blockIdx.x;
  const int t = threadIdx.x;
  __shared__ float s_pool[64], s_a[16], s_att[128], s_sp[9], s_k[4], s_h[8],
      s_att2[128], s_red[2], s_w12[2];

  if (t < 64) s_pool[t] = ws[WS_POOLED + b * 64 + t];
  __syncthreads();

  if (t < 16) {
    float s = 0.f;
    for (int c = 0; c < 64; ++c) s += s_pool[c] * fc_w[t * 64 + c];
    s_a[t] = fmaxf(s, 0.f);
  }
  __syncthreads();

  if (t < 64) {
    float s = ch_b[t];
    for (int j = 0; j < 16; ++j) s += s_a[j] * ch_w[t * 16 + j];
    s_att[t] = 1.f / (1.f + expf(-s));
  } else {
    const int o = t - 64;
    float s = f_b[o];
    for (int j = 0; j < 16; ++j) s += s_a[j] * f_w[o * 16 + j];
    s_att[t] = 1.f / (1.f + expf(-s));
  }
  if (t < 9) {
    float s = sp_b[t];
    for (int j = 0; j < 16; ++j) s += s_a[j] * sp_w[t * 16 + j];
    s_sp[t] = 1.f / (1.f + expf(-s));
  }
  if (t < 4) {
    float s = k_b[t];
    for (int j = 0; j < 16; ++j) s += s_a[j] * k_w[t * 16 + j];
    s_k[t] = s;
  }
  __syncthreads();

  if (t < 8) {
    float s = fus_b1[t];
    for (int c = 0; c < 128; ++c) s += s_att[c] * fus_w1[t * 128 + c];
    s_h[t] = fmaxf(s, 0.f);
  }
  if (t == 127) {
    float m = fmaxf(fmaxf(s_k[0], s_k[1]), fmaxf(s_k[2], s_k[3]));
    float e0 = expf(s_k[0] - m), e1 = expf(s_k[1] - m);
    float e2 = expf(s_k[2] - m), e3 = expf(s_k[3] - m);
    float inv = 1.f / (e0 + e1 + e2 + e3);
    s_k[0] = e0 * inv; s_k[1] = e1 * inv; s_k[2] = e2 * inv; s_k[3] = e3 * inv;
  }
  __syncthreads();

  {
    float s = fus_b2[t];
    for (int j = 0; j < 8; ++j) s += s_h[j] * fus_w2[t * 8 + j];
    s_att2[t] = 1.f / (1.f + expf(-s));
  }
  __syncthreads();

  if (t < 2) {
    float s = 0.f;
    for (int c = 0; c < 64; ++c) s += s_att2[t * 64 + c];
    s_red[t] = s;
  }
  __syncthreads();
  if (t == 0) {
    float m = fmaxf(s_red[0], s_red[1]);
    float e1 = expf(s_red[0] - m), e2 = expf(s_red[1] - m);
    float inv = 1.f / (e1 + e2);
    s_w12[0] = e1 * inv;
    s_w12[1] = e2 * inv;
  }
  __syncthreads();

  if (t < 64) {
    ws[WS_CIN  + b * 64 + t] = s_w12[0] * s_att[t];
    ws[WS_COUT + b * 64 + t] = s_w12[1] * s_att[64 + t];
  }
  if (t < 9) ws[WS_SP9 + b * 9 + t] = s_sp[t];
  if (t < 4) ws[WS_K4 + b * 4 + t] = s_k[t];
}

// ---------------- 3) fused per-sample weight -> bf16 [b][pq][o][i] ----------------
__global__ __launch_bounds__(256) void wf_kernel(const float* __restrict__ weight,
                                                 const float* __restrict__ ws,
                                                 unsigned short* __restrict__ wfb) {
  const int bo = blockIdx.x;              // b*64 + o
  const int b = bo >> 6, o = bo & 63;
  const float co = ws[WS_COUT + b * 64 + o];
  const float k0 = ws[WS_K4 + b * 4 + 0], k1 = ws[WS_K4 + b * 4 + 1];
  const float k2 = ws[WS_K4 + b * 4 + 2], k3 = ws[WS_K4 + b * 4 + 3];
  for (int idx = threadIdx.x; idx < 576; idx += 256) {
    const int pq = idx >> 6, i = idx & 63;
    const size_t wi = ((size_t)o * 64 + i) * 9 + pq;
    float s = k0 * weight[wi] + k1 * weight[36864 + wi] +
              k2 * weight[73728 + wi] + k3 * weight[110592 + wi];
    float v = co * ws[WS_SP9 + b * 9 + pq] * ws[WS_CIN + b * 64 + i] * s;
    wfb[((size_t)(b * 9 + pq) * 64 + o) * 64 + i] = (unsigned short)f2bf(v);
  }
}

// ---------------- 4) implicit-GEMM conv via MFMA 32x32x16 bf16 ----------------
// block: 512 thr (8 waves), one batch, 4 output rows x 128 cols, all 64 oc.
// wave: 1 row x 128 cols x 32 oc -> 4 C-frags (f32x16).
// LDS: x tile [pix = 6 rows * 132 cols][16 ci] bf16, swizzled; wf [9*64][16 ci].
__global__ __launch_bounds__(512, 2) void conv_kernel(const float* __restrict__ x,
                                                      const unsigned short* __restrict__ wfb,
                                                      float* __restrict__ out) {
  const int b  = blockIdx.x >> 5;
  const int h0 = (blockIdx.x & 31) << 2;
  const int tid = threadIdx.x;
  const int lane = tid & 63;
  const int wid = tid >> 6;
  const int rw = wid >> 1;              // wave's output row (0..3)
  const int obase = (wid & 1) << 5;     // wave's 32-oc half
  const int l31 = lane & 31;
  const int hi = lane >> 5;

  __shared__ __align__(16) short sx[6 * 132 * 16];   // 25344 B
  __shared__ __align__(16) short swf[576 * 16];      // 18432 B

  f32x16 acc[4];
#pragma unroll
  for (int nt = 0; nt < 4; ++nt)
#pragma unroll
    for (int r = 0; r < 16; ++r) acc[nt][r] = 0.f;

  for (int ch = 0; ch < 4; ++ch) {
    const int c0 = ch << 4;
    __syncthreads();
    // ---- stage x chunk: 6 rows x 132 cols x 16 ci, transposed to [pix][ci] bf16
    for (int idx = tid; idx < 1584; idx += 512) {
      const int c = idx % 132;
      const int t = idx / 132;          // 0..11
      const int r = t % 6;
      const int h8 = t / 6;             // which 8-ci half
      const int gr = h0 - 1 + r, gc = c - 1;
      uint4 v = make_uint4(0u, 0u, 0u, 0u);
      if ((unsigned)gr < 128u && (unsigned)gc < 128u) {
        const float* xp = x + (((size_t)(b * 64 + c0 + h8 * 8) * 128 + gr) * 128 + gc);
        v.x = f2bf(xp[0])          | (f2bf(xp[16384])     << 16);
        v.y = f2bf(xp[2 * 16384])  | (f2bf(xp[3 * 16384]) << 16);
        v.z = f2bf(xp[4 * 16384])  | (f2bf(xp[5 * 16384]) << 16);
        v.w = f2bf(xp[6 * 16384])  | (f2bf(xp[7 * 16384]) << 16);
      }
      const int pix = r * 132 + c;
      const int byteoff = (pix * 32 + h8 * 16) ^ ((pix & 4) << 2);
      *(uint4*)((char*)sx + byteoff) = v;
    }
    // ---- stage wf chunk: [pq*64+o][16 ci]
    for (int idx = tid; idx < 1152; idx += 512) {
      const int row = idx >> 1, h8 = idx & 1;
      uint4 v = *(const uint4*)(wfb + (((size_t)b * 576 + row) * 64 + c0 + h8 * 8));
      const int byteoff = (row * 32 + h8 * 16) ^ ((row & 4) << 2);
      *(uint4*)((char*)swf + byteoff) = v;
    }
    __syncthreads();

    // ---- 9 taps x 4 N-tiles of MFMA
#pragma unroll
    for (int p = 0; p < 3; ++p) {
#pragma unroll
      for (int q = 0; q < 3; ++q) {
        const int arow = (p * 3 + q) * 64 + obase + l31;
        const int abyte = (arow * 32 + hi * 16) ^ ((arow & 4) << 2);
        bf16x8 af = *(const bf16x8*)((const char*)swf + abyte);
#pragma unroll
        for (int nt = 0; nt < 4; ++nt) {
          const int pix = (rw + p) * 132 + nt * 32 + q + l31;
          const int bbyte = (pix * 32 + hi * 16) ^ ((pix & 4) << 2);
          bf16x8 bf = *(const bf16x8*)((const char*)sx + bbyte);
          acc[nt] = __builtin_amdgcn_mfma_f32_32x32x16_bf16(af, bf, acc[nt], 0, 0, 0);
        }
      }
    }
  }

  const int h = h0 + rw;
#pragma unroll
  for (int nt = 0; nt < 4; ++nt) {
    const int col = nt * 32 + l31;
#pragma unroll
    for (int reg = 0; reg < 16; ++reg) {
      const int o = obase + (reg & 3) + ((reg >> 2) << 3) + (hi << 2);
      out[(((size_t)(b * 64 + o)) * 128 + h) * 128 + col] = acc[nt][reg];
    }
  }
}

extern "C" void kernel_launch(void* const* d_in, const int* in_sizes, int n_in,
                              void* d_out, int out_size, void* d_ws, size_t ws_size,
                              hipStream_t stream) {
  const float* x      = (const float*)d_in[0];
  const float* fc_w   = (const float*)d_in[1];
  const float* ch_w   = (const float*)d_in[2];
  const float* ch_b   = (const float*)d_in[3];
  const float* f_w    = (const float*)d_in[4];
  const float* f_b    = (const float*)d_in[5];
  const float* sp_w   = (const float*)d_in[6];
  const float* sp_b   = (const float*)d_in[7];
  const float* k_w    = (const float*)d_in[8];
  const float* k_b    = (const float*)d_in[9];
  const float* fus_w1 = (const float*)d_in[10];
  const float* fus_b1 = (const float*)d_in[11];
  const float* fus_w2 = (const float*)d_in[12];
  const float* fus_b2 = (const float*)d_in[13];
  const float* weight = (const float*)d_in[14];
  float* ws  = (float*)d_ws;
  float* out = (float*)d_out;
  unsigned short* wfb = (unsigned short*)(ws + WS_WF);

  pool_kernel<<<2048, 256, 0, stream>>>(x, ws + WS_POOLED);
  att_kernel<<<32, 128, 0, stream>>>(fc_w, ch_w, ch_b, f_w, f_b, sp_w, sp_b,
                                     k_w, k_b, fus_w1, fus_b1, fus_w2, fus_b2, ws);
  wf_kernel<<<2048, 256, 0, stream>>>(weight, ws, wfb);
  conv_kernel<<<1024, 512, 0, stream>>>(x, wfb, out);
}